// Round 1
// baseline (82.273 us; speedup 1.0000x reference)
//
#include <hip/hip_runtime.h>

// CutOut: images [B=64, H=512, W=512, C=3] fp32, NHWC.
// Zero a (2*half)×(2*half) square centered at (cy[b], cx[b]) per image.
// half = length/2, length read from device scalar.
//
// Pure memory-bound masked copy. float4-vectorized grid-stride loop:
//   floats/image = 512*512*3 = 786432  -> 196608 float4
//   floats/row   = 512*3     = 1536    -> 384   float4
// Total float4 = 12,582,912 (exactly divisible — no tail handling).

__global__ __launch_bounds__(256) void cutout_kernel(
    const float4* __restrict__ in, float4* __restrict__ out,
    const int* __restrict__ cy, const int* __restrict__ cx,
    const int* __restrict__ len_p, int total4)
{
    const int F4_PER_IMG = 196608;  // (512*512*3)/4
    const int F4_PER_ROW = 384;     // (512*3)/4

    const int half = len_p[0] >> 1;

    int idx    = blockIdx.x * blockDim.x + threadIdx.x;
    int stride = gridDim.x * blockDim.x;

    for (int i = idx; i < total4; i += stride) {
        float4 v = in[i];

        int b   = i / F4_PER_IMG;          // magic-multiply
        int rem = i - b * F4_PER_IMG;
        int h   = rem / F4_PER_ROW;        // magic-multiply
        int r4  = rem - h * F4_PER_ROW;    // float4 index within row

        int ycy = cy[b];                   // wave-uniform per image (mostly)
        if (h >= ycy - half && h < ycy + half) {
            // Row intersects the cutout (~10% of rows). Per-element column test:
            // element k at row-float-offset base+k belongs to column (base+k)/3.
            int xcx = cx[b];
            int lo = xcx - half, hi = xcx + half;
            int base = r4 * 4;
            int w0 = (base    ) / 3;
            int w1 = (base + 1) / 3;
            int w2 = (base + 2) / 3;
            int w3 = (base + 3) / 3;
            if (w0 >= lo && w0 < hi) v.x = 0.0f;
            if (w1 >= lo && w1 < hi) v.y = 0.0f;
            if (w2 >= lo && w2 < hi) v.z = 0.0f;
            if (w3 >= lo && w3 < hi) v.w = 0.0f;
        }

        out[i] = v;
    }
}

extern "C" void kernel_launch(void* const* d_in, const int* in_sizes, int n_in,
                              void* d_out, int out_size, void* d_ws, size_t ws_size,
                              hipStream_t stream) {
    const float* images = (const float*)d_in[0];
    const int*   cy     = (const int*)d_in[1];
    const int*   cx     = (const int*)d_in[2];
    const int*   len_p  = (const int*)d_in[3];

    const int total4 = out_size / 4;   // 12,582,912

    const int block = 256;
    // Memory-bound streaming: cap grid and grid-stride (≈8 blocks/CU · 256 CU).
    int grid = (total4 + block - 1) / block;
    if (grid > 2048) grid = 2048;

    cutout_kernel<<<grid, block, 0, stream>>>(
        (const float4*)images, (float4*)d_out, cy, cx, len_p, total4);
}

// Round 2
// 72.904 us; speedup vs baseline: 1.1285x; 1.1285x over previous
//
#include <hip/hip_runtime.h>

// CutOut: images [B=64, H=512, W=512, C=3] fp32, NHWC.
// Zero a (2*half)x(2*half) square centered at (cy[b], cx[b]) per image.
//
// Pure memory-bound masked copy, direct-mapped:
//   one workgroup per image row: grid = B*H = 32768, block = 384 threads,
//   each thread copies exactly one float4 (row = 512*3 floats = 384 float4).
// Index math is shift/mask of blockIdx.x (wave-uniform -> scalar regs);
// cy/cx/len loads scalarize. Only ~10% of rows (length/H) take the
// per-element column-test branch.

__global__ __launch_bounds__(384) void cutout_rows(
    const float4* __restrict__ in, float4* __restrict__ out,
    const int* __restrict__ cy, const int* __restrict__ cx,
    const int* __restrict__ len_p)
{
    const int row = blockIdx.x;          // 0 .. B*H-1
    const int b   = row >> 9;            // H = 512
    const int h   = row & 511;
    const int r4  = threadIdx.x;         // 0 .. 383
    const int gi  = row * 384 + r4;      // global float4 index (< 2^24)

    float4 v = in[gi];

    const int half = len_p[0] >> 1;      // scalar load (uniform)
    const int ycy  = cy[b];              // scalar load (b uniform per block)
    if (h >= ycy - half && h < ycy + half) {
        // Row intersects the cutout. Element k at row float offset base+k
        // belongs to image column (base+k)/3  (C = 3).
        const int xcx = cx[b];
        const int lo = xcx - half, hi = xcx + half;
        const int base = r4 * 4;
        const int w0 = (base    ) / 3;
        const int w1 = (base + 1) / 3;
        const int w2 = (base + 2) / 3;
        const int w3 = (base + 3) / 3;
        if (w0 >= lo && w0 < hi) v.x = 0.0f;
        if (w1 >= lo && w1 < hi) v.y = 0.0f;
        if (w2 >= lo && w2 < hi) v.z = 0.0f;
        if (w3 >= lo && w3 < hi) v.w = 0.0f;
    }

    out[gi] = v;
}

extern "C" void kernel_launch(void* const* d_in, const int* in_sizes, int n_in,
                              void* d_out, int out_size, void* d_ws, size_t ws_size,
                              hipStream_t stream) {
    const float* images = (const float*)d_in[0];
    const int*   cy     = (const int*)d_in[1];
    const int*   cx     = (const int*)d_in[2];
    const int*   len_p  = (const int*)d_in[3];

    const int B = 64, H = 512;
    const int grid  = B * H;   // 32768 row-blocks
    const int block = 384;     // 384 float4 per row

    cutout_rows<<<grid, block, 0, stream>>>(
        (const float4*)images, (float4*)d_out, cy, cx, len_p);
}

// Round 3
// 68.242 us; speedup vs baseline: 1.2056x; 1.0683x over previous
//
#include <hip/hip_runtime.h>

// CutOut: images [B=64, H=512, W=512, C=3] fp32, NHWC.
// Zero a (2*half)x(2*half) square centered at (cy[b], cx[b]) per image.
//
// Streaming masked copy at the HBM roofline:
//  - one workgroup = 4 consecutive rows of one image (b uniform per block)
//  - 384 threads/block, each thread owns one float4 column-slot in each of
//    the 4 rows -> 4 back-to-back nt loads (4 KB in flight per wave), then
//    4 nt stores. Column predicates depend only on threadIdx -> computed
//    once, reused across rows. Row tests are scalar (uniform).
//  - non-temporal: 402 MB streamed with zero reuse; skip cache allocation.

typedef float f32x4 __attribute__((ext_vector_type(4)));

__global__ __launch_bounds__(384) void cutout_rows4(
    const f32x4* __restrict__ in, f32x4* __restrict__ out,
    const int* __restrict__ cy, const int* __restrict__ cx,
    const int* __restrict__ len_p)
{
    const int blk = blockIdx.x;            // 0 .. B*H/4 - 1   (8192)
    const int b   = blk >> 7;              // 128 blocks per image (512/4)
    const int h0  = (blk & 127) << 2;      // first of 4 rows
    const int r4  = threadIdx.x;           // 0 .. 383 (float4 slot in row)
    const int gi0 = blk * 1536 + r4;       // 4 rows * 384 float4

    f32x4 v0 = __builtin_nontemporal_load(&in[gi0       ]);
    f32x4 v1 = __builtin_nontemporal_load(&in[gi0 +  384]);
    f32x4 v2 = __builtin_nontemporal_load(&in[gi0 +  768]);
    f32x4 v3 = __builtin_nontemporal_load(&in[gi0 + 1152]);

    const int half = len_p[0] >> 1;        // uniform scalar
    const int ycy  = cy[b];                // uniform scalar (b block-uniform)
    const int lo_r = ycy - half, hi_r = ycy + half;

    if (h0 + 3 >= lo_r && h0 < hi_r) {     // any of the 4 rows in cutout?
        const int xcx = cx[b];
        const int lo = xcx - half, hi = xcx + half;
        const int base = r4 * 4;           // element k -> column (base+k)/3
        const bool c0 = ((base    ) / 3 >= lo) && ((base    ) / 3 < hi);
        const bool c1 = ((base + 1) / 3 >= lo) && ((base + 1) / 3 < hi);
        const bool c2 = ((base + 2) / 3 >= lo) && ((base + 2) / 3 < hi);
        const bool c3 = ((base + 3) / 3 >= lo) && ((base + 3) / 3 < hi);

        if (h0     >= lo_r && h0     < hi_r) {
            if (c0) v0.x = 0.0f; if (c1) v0.y = 0.0f;
            if (c2) v0.z = 0.0f; if (c3) v0.w = 0.0f;
        }
        if (h0 + 1 >= lo_r && h0 + 1 < hi_r) {
            if (c0) v1.x = 0.0f; if (c1) v1.y = 0.0f;
            if (c2) v1.z = 0.0f; if (c3) v1.w = 0.0f;
        }
        if (h0 + 2 >= lo_r && h0 + 2 < hi_r) {
            if (c0) v2.x = 0.0f; if (c1) v2.y = 0.0f;
            if (c2) v2.z = 0.0f; if (c3) v2.w = 0.0f;
        }
        if (h0 + 3 >= lo_r && h0 + 3 < hi_r) {
            if (c0) v3.x = 0.0f; if (c1) v3.y = 0.0f;
            if (c2) v3.z = 0.0f; if (c3) v3.w = 0.0f;
        }
    }

    __builtin_nontemporal_store(v0, &out[gi0       ]);
    __builtin_nontemporal_store(v1, &out[gi0 +  384]);
    __builtin_nontemporal_store(v2, &out[gi0 +  768]);
    __builtin_nontemporal_store(v3, &out[gi0 + 1152]);
}

extern "C" void kernel_launch(void* const* d_in, const int* in_sizes, int n_in,
                              void* d_out, int out_size, void* d_ws, size_t ws_size,
                              hipStream_t stream) {
    const float* images = (const float*)d_in[0];
    const int*   cy     = (const int*)d_in[1];
    const int*   cx     = (const int*)d_in[2];
    const int*   len_p  = (const int*)d_in[3];

    const int B = 64, H = 512;
    const int grid  = (B * H) / 4;   // 8192 blocks, 4 rows each
    const int block = 384;

    cutout_rows4<<<grid, block, 0, stream>>>(
        (const f32x4*)images, (f32x4*)d_out, cy, cx, len_p);
}